// Round 2
// baseline (198.219 us; speedup 1.0000x reference)
//
#include <hip/hip_runtime.h>
#include <cfloat>

namespace {
constexpr int H = 256;
constexpr int A = 4096;
constexpr int B = 32;
constexpr int G = 512;
constexpr int K = 16;
constexpr size_t SLICE = (size_t)A * H;   // elements per batch slice = 1,048,576
}

static __device__ __forceinline__ float4 f4max(float4 a, float4 b) {
    float4 r;
    r.x = fmaxf(a.x, b.x);
    r.y = fmaxf(a.y, b.y);
    r.z = fmaxf(a.z, b.z);
    r.w = fmaxf(a.w, b.w);
    return r;
}

// Fused gather-max: out[g,h] = max_{b,k} x[b, idx[g,k], h].
// One block per g (512 blocks x 256 threads). Wave w handles batches
// [8w, 8w+8); lane i owns the float4 at h = 4*i, so each (wave, k, b) load is
// one fully-coalesced 1 KiB transaction. Only referenced rows of x are ever
// touched (~86.5% of the 128 MiB), and repeated references hit L2/L3.
// Cross-wave combine via one LDS round.
__global__ __launch_bounds__(256) void fused_kernel(const float* __restrict__ x,
                                                    const int* __restrict__ idx,
                                                    float* __restrict__ out) {
    const int g    = blockIdx.x;
    const int lane = threadIdx.x & 63;
    const int wave = threadIdx.x >> 6;
    const int h4   = lane << 2;
    const int b0   = wave * 8;

    // Preload the 16 wave-uniform row indices (scalar loads, K$-resident).
    int rows[K];
#pragma unroll
    for (int k = 0; k < K; ++k) rows[k] = idx[g * K + k];

    float4 m0 = make_float4(-FLT_MAX, -FLT_MAX, -FLT_MAX, -FLT_MAX);
    float4 m1 = m0;

    for (int k = 0; k < K; ++k) {
        const float* p = x + (size_t)b0 * SLICE + (size_t)rows[k] * H + h4;
#pragma unroll
        for (int b = 0; b < 8; b += 2) {
            float4 v0 = *(const float4*)(p + (size_t)b * SLICE);
            float4 v1 = *(const float4*)(p + (size_t)(b + 1) * SLICE);
            m0 = f4max(m0, v0);
            m1 = f4max(m1, v1);
        }
    }
    float4 m = f4max(m0, m1);

    __shared__ float4 part[4][64];
    part[wave][lane] = m;
    __syncthreads();
    if (wave == 0) {
        float4 r = f4max(f4max(part[0][lane], part[1][lane]),
                         f4max(part[2][lane], part[3][lane]));
        *(float4*)(out + (size_t)g * H + h4) = r;
    }
}

extern "C" void kernel_launch(void* const* d_in, const int* in_sizes, int n_in,
                              void* d_out, int out_size, void* d_ws, size_t ws_size,
                              hipStream_t stream) {
    const float* x   = (const float*)d_in[0];
    const int*   idx = (const int*)d_in[1];
    float*       out = (float*)d_out;
    (void)d_ws; (void)ws_size;

    fused_kernel<<<G, 256, 0, stream>>>(x, idx, out);
}

// Round 3
// 196.432 us; speedup vs baseline: 1.0091x; 1.0091x over previous
//
#include <hip/hip_runtime.h>
#include <cfloat>

namespace {
constexpr int H = 256;
constexpr int A = 4096;
constexpr int B = 32;
constexpr int G = 512;
constexpr int K = 16;
constexpr size_t SLICE = (size_t)A * H;   // elements per batch slice = 1,048,576
}

static __device__ __forceinline__ float4 f4max(float4 a, float4 b) {
    float4 r;
    r.x = fmaxf(a.x, b.x);
    r.y = fmaxf(a.y, b.y);
    r.z = fmaxf(a.z, b.z);
    r.w = fmaxf(a.w, b.w);
    return r;
}

// Phase 0: build referenced-row bitmap (one byte per row; ws is poisoned to
// 0xAA every iteration, so zero it here first). 1 block x 256 threads.
__global__ __launch_bounds__(256) void bitmap_kernel(const int* __restrict__ idx,
                                                     unsigned char* __restrict__ bm) {
    const int t = threadIdx.x;
#pragma unroll
    for (int i = 0; i < A / 256; ++i) bm[t + i * 256] = 0;
    __syncthreads();
#pragma unroll
    for (int i = 0; i < (G * K) / 256; ++i) bm[idx[t + i * 256]] = 1;  // benign races
}

// Phase 1: rowmax[a*H + h] = max_b x[b*SLICE + a*H + h], skipping rows no
// group references. Each wave owns exactly one row (64 lanes x float4 =
// 256 floats = 1 KiB per b), so both the loads and the skip branch are
// wave-uniform. Pure HBM streaming for ~86.5% of the 128 MiB input.
__global__ __launch_bounds__(256) void rowmax_kernel(const float* __restrict__ x,
                                                     const unsigned char* __restrict__ bm,
                                                     float* __restrict__ rowmax) {
    const int t   = blockIdx.x * 256 + threadIdx.x;  // 0 .. A*H/4 - 1
    const int row = t >> 6;                          // wave-uniform row id
    if (bm[row] == 0) return;                        // wave-uniform skip

    const size_t off = (size_t)t << 2;
    const float* p = x + off;

    float4 m0 = *(const float4*)p;
    float4 m1 = *(const float4*)(p + SLICE);
#pragma unroll
    for (int b = 2; b < B; b += 2) {
        float4 v0 = *(const float4*)(p + (size_t)b * SLICE);
        float4 v1 = *(const float4*)(p + (size_t)(b + 1) * SLICE);
        m0 = f4max(m0, v0);
        m1 = f4max(m1, v1);
    }
    *(float4*)(rowmax + off) = f4max(m0, m1);
}

// Phase 2: out[g*H + h] = max_k rowmax[idx[g*K+k]*H + h].
// rowmax is 4 MiB -> L2/L3 resident; ~2 us.
__global__ __launch_bounds__(64) void gather_kernel(const float* __restrict__ rowmax,
                                                    const int* __restrict__ idx,
                                                    float* __restrict__ out) {
    const int g  = blockIdx.x;
    const int h4 = threadIdx.x << 2;

    float4 m = make_float4(-FLT_MAX, -FLT_MAX, -FLT_MAX, -FLT_MAX);
#pragma unroll
    for (int k = 0; k < K; ++k) {
        const int r = idx[g * K + k];                 // wave-uniform load
        float4 v = *(const float4*)(rowmax + (size_t)r * H + h4);
        m = f4max(m, v);
    }
    *(float4*)(out + (size_t)g * H + h4) = m;
}

extern "C" void kernel_launch(void* const* d_in, const int* in_sizes, int n_in,
                              void* d_out, int out_size, void* d_ws, size_t ws_size,
                              hipStream_t stream) {
    const float* x   = (const float*)d_in[0];
    const int*   idx = (const int*)d_in[1];
    float*       out = (float*)d_out;

    // ws layout: [0, 4 MiB) rowmax, [4 MiB, 4 MiB + 4 KiB) bitmap
    float*         rowmax = (float*)d_ws;
    unsigned char* bm     = (unsigned char*)d_ws + (size_t)A * H * sizeof(float);

    bitmap_kernel<<<1, 256, 0, stream>>>(idx, bm);
    rowmax_kernel<<<(A * H / 4) / 256, 256, 0, stream>>>(x, bm, rowmax);
    gather_kernel<<<G, 64, 0, stream>>>(rowmax, idx, out);
}

// Round 4
// 187.461 us; speedup vs baseline: 1.0574x; 1.0479x over previous
//
#include <hip/hip_runtime.h>
#include <cfloat>

namespace {
constexpr int H = 256;
constexpr int A = 4096;
constexpr int B = 32;
constexpr int G = 512;
constexpr int K = 16;
constexpr size_t SLICE = (size_t)A * H;   // elements per batch slice = 1,048,576
}

static __device__ __forceinline__ float4 f4max(float4 a, float4 b) {
    float4 r;
    r.x = fmaxf(a.x, b.x);
    r.y = fmaxf(a.y, b.y);
    r.z = fmaxf(a.z, b.z);
    r.w = fmaxf(a.w, b.w);
    return r;
}

static __device__ __forceinline__ float4 ntload4(const float* p) {
    // Non-temporal 16B load: x is streamed once with zero reuse; keep it from
    // evicting the rowmax lines (phase-2's working set) out of L2.
    float4 v;
    v.x = __builtin_nontemporal_load(p + 0);
    v.y = __builtin_nontemporal_load(p + 1);
    v.z = __builtin_nontemporal_load(p + 2);
    v.w = __builtin_nontemporal_load(p + 3);
    return v;
}

// Phase 1: rowmax[a*H + h] = max_b x[b*SLICE + a*H + h]
// 1024 blocks x 256 threads; each thread owns one float4. A wave's 64 lanes
// cover exactly one 256-float row slice -> every load is a fully coalesced
// contiguous 1 KiB transaction. Pure HBM streaming (~128 MiB read, 4 MiB write).
__global__ __launch_bounds__(256) void rowmax_kernel(const float* __restrict__ x,
                                                     float* __restrict__ rowmax) {
    const int t  = blockIdx.x * 256 + threadIdx.x;   // 0 .. A*H/4 - 1
    const size_t off = (size_t)t << 2;               // element offset into one slice
    const float* p = x + off;

    // two accumulators to shorten the fmax dependency chain
    float4 m0 = ntload4(p);
    float4 m1 = ntload4(p + SLICE);
#pragma unroll
    for (int b = 2; b < B; b += 2) {
        float4 v0 = ntload4(p + (size_t)b * SLICE);
        float4 v1 = ntload4(p + (size_t)(b + 1) * SLICE);
        m0 = f4max(m0, v0);
        m1 = f4max(m1, v1);
    }
    *(float4*)(rowmax + off) = f4max(m0, m1);
}

// Phase 2: out[g*H + h] = max_k rowmax[idx[g*K+k]*H + h]
// rowmax is 4 MiB -> L2-resident (nt loads above keep it there); ~2 us.
__global__ __launch_bounds__(64) void gather_kernel(const float* __restrict__ rowmax,
                                                    const int* __restrict__ idx,
                                                    float* __restrict__ out) {
    const int g  = blockIdx.x;
    const int h4 = threadIdx.x << 2;

    float4 m = make_float4(-FLT_MAX, -FLT_MAX, -FLT_MAX, -FLT_MAX);
#pragma unroll
    for (int k = 0; k < K; ++k) {
        const int r = idx[g * K + k];                 // wave-uniform load
        float4 v = *(const float4*)(rowmax + (size_t)r * H + h4);
        m = f4max(m, v);
    }
    *(float4*)(out + (size_t)g * H + h4) = m;
}

extern "C" void kernel_launch(void* const* d_in, const int* in_sizes, int n_in,
                              void* d_out, int out_size, void* d_ws, size_t ws_size,
                              hipStream_t stream) {
    const float* x   = (const float*)d_in[0];
    const int*   idx = (const int*)d_in[1];
    float*       out = (float*)d_out;

    float* rowmax = (float*)d_ws;  // 4 MiB scratch
    rowmax_kernel<<<(A * H / 4) / 256, 256, 0, stream>>>(x, rowmax);
    gather_kernel<<<G, 64, 0, stream>>>(rowmax, idx, out);
}